// Round 1
// baseline (20.655 us; speedup 1.0000x reference)
//
#include <hip/hip_runtime.h>

#define NB 4
#define NH 64
#define NW 64
#define NPIX (NH * NW)   // 4096 pixels per batch
#define NCEN NPIX        // 4096 candidate centers per batch

// Block = 256 threads. Grid = NB * NH = 256 blocks (one block per (batch,row)).
// Each block: stage all centers of its batch in LDS, 4 threads per pixel each
// scan 1024 centers for min-d2, combine, fused sigmoid+sq-err, reduce to 1
// partial per block.
__global__ __launch_bounds__(256) void cal_main_kernel(
    const float* __restrict__ att,   // [B,1,H,W] logits
    const int*   __restrict__ cls,   // [B,H,W]
    const float* __restrict__ box,   // [B,H,W,2] (cx,cy)
    float* __restrict__ partial)     // [NB*NH]
{
    __shared__ float2 cen[NCEN];     // 32 KiB
    __shared__ float  red[256];

    const int blk = blockIdx.x;
    const int b   = blk >> 6;        // / NH
    const int row = blk & 63;        // % NH  (y coordinate)
    const int tid = threadIdx.x;

    // Cooperative load of all 4096 centers; invalid -> far away (exp -> 0).
    const float2* boxb = (const float2*)(box + (size_t)b * NCEN * 2);
    const int*    clsb = cls + (size_t)b * NCEN;
    #pragma unroll
    for (int i = 0; i < 16; ++i) {
        int n = tid + i * 256;
        float2 c = boxb[n];
        if (clsb[n] <= 0) { c.x = 1e18f; c.y = 1e18f; }
        cen[n] = c;
    }
    __syncthreads();

    const int pix = tid & 63;        // x coordinate
    const int sub = tid >> 6;        // which quarter of the centers
    const float px = (float)pix;
    const float py = (float)row;

    // 4 independent min accumulators to break the v_min dependency chain.
    float m0 = 3.4e38f, m1 = 3.4e38f, m2 = 3.4e38f, m3 = 3.4e38f;
    const int base = sub * (NCEN / 4);
    #pragma unroll 2
    for (int i = 0; i < NCEN / 4; i += 4) {
        float2 c0 = cen[base + i + 0];
        float2 c1 = cen[base + i + 1];
        float2 c2 = cen[base + i + 2];
        float2 c3 = cen[base + i + 3];
        float dx, dy, d2;
        dx = px - c0.x; dy = py - c0.y; d2 = dx*dx + dy*dy; m0 = fminf(m0, d2);
        dx = px - c1.x; dy = py - c1.y; d2 = dx*dx + dy*dy; m1 = fminf(m1, d2);
        dx = px - c2.x; dy = py - c2.y; d2 = dx*dx + dy*dy; m2 = fminf(m2, d2);
        dx = px - c3.x; dy = py - c3.y; d2 = dx*dx + dy*dy; m3 = fminf(m3, d2);
    }
    float m = fminf(fminf(m0, m1), fminf(m2, m3));
    red[tid] = m;
    __syncthreads();

    if (tid < 64) {   // exactly wave 0
        m = fminf(fminf(red[tid], red[tid + 64]),
                  fminf(red[tid + 128], red[tid + 192]));
        // heat = max_n exp(-d2/ (2*sigma^2)), sigma=2 -> exp(-min_d2 * 0.125)
        float heat = expf(-m * 0.125f);
        float a = att[(size_t)b * NPIX + row * NW + pix];
        float s = 1.0f / (1.0f + expf(-a));   // sigmoid
        float d = s - heat;
        float sq = d * d;
        // full-wave (64 lane) shuffle reduction
        #pragma unroll
        for (int off = 32; off > 0; off >>= 1)
            sq += __shfl_down(sq, off);
        if (tid == 0) partial[blk] = sq;
    }
}

__global__ __launch_bounds__(256) void cal_final_kernel(
    const float* __restrict__ partial,  // [256]
    float* __restrict__ out)            // [1]
{
    const int tid = threadIdx.x;
    float v = partial[tid];
    #pragma unroll
    for (int off = 32; off > 0; off >>= 1)
        v += __shfl_down(v, off);
    __shared__ float red[4];
    if ((tid & 63) == 0) red[tid >> 6] = v;
    __syncthreads();
    if (tid == 0) {
        float t = red[0] + red[1] + red[2] + red[3];
        // loss = mean * WEIGHT = (sum / (B*H*W)) * 0.05
        out[0] = t * (0.05f / (float)(NB * NPIX));
    }
}

extern "C" void kernel_launch(void* const* d_in, const int* in_sizes, int n_in,
                              void* d_out, int out_size, void* d_ws, size_t ws_size,
                              hipStream_t stream) {
    const float* att = (const float*)d_in[0];   // attention_maps [4,1,64,64] f32
    const int*   cls = (const int*)  d_in[1];   // class_targets  [4,64,64]  i32
    const float* box = (const float*)d_in[2];   // box_targets    [4,64,64,2] f32
    float* out = (float*)d_out;
    float* partial = (float*)d_ws;              // 256 floats

    cal_main_kernel<<<NB * NH, 256, 0, stream>>>(att, cls, box, partial);
    cal_final_kernel<<<1, 256, 0, stream>>>(partial, out);
}

// Round 2
// 13.527 us; speedup vs baseline: 1.5269x; 1.5269x over previous
//
#include <hip/hip_runtime.h>

#define NB 4
#define NH 64
#define NW 64
#define NPIX (NH * NW)   // 4096 pixels per batch
#define NCEN NPIX        // 4096 candidate centers per batch

// Grid = 256 blocks (one per (batch,row)), 1024 threads = 16 waves = 4/SIMD.
// Phase 1: compact valid centers (cls>0) of this batch into LDS (order-free:
//   min over d2 is commutative/exact, so atomic slot order doesn't change the
//   bitwise result).
// Phase 2: wave w scans compacted chunk [w*CH,(w+1)*CH), lane = pixel x.
//   All lanes read the same center -> LDS broadcast, conflict-free.
// Phase 3: 16-way fmin combine, heat=exp(-min_d2/8), fused sigmoid + sq-err,
//   64-lane shuffle sum -> 1 partial per block.
__global__ __launch_bounds__(1024) void cal_main_kernel(
    const float* __restrict__ att,   // [B,1,H,W] logits
    const int*   __restrict__ cls,   // [B,H,W]
    const float* __restrict__ box,   // [B,H,W,2] (cx,cy)
    float* __restrict__ partial)     // [NB*NH]
{
    __shared__ float2 cen[NCEN + 128];   // compacted centers + pad
    __shared__ float  red[1024];
    __shared__ int    cnt;

    const int blk  = blockIdx.x;
    const int b    = blk >> 6;           // batch
    const int row  = blk & 63;           // y
    const int tid  = threadIdx.x;
    const int lane = tid & 63;
    const int wave = tid >> 6;           // 0..15

    if (tid == 0) cnt = 0;
    __syncthreads();

    // ---- Phase 1: compacting stage of valid centers ----
    const float2* boxb = (const float2*)(box + (size_t)b * NCEN * 2);
    const int*    clsb = cls + (size_t)b * NCEN;
    #pragma unroll
    for (int i = 0; i < 4; ++i) {
        int n = tid + i * 1024;
        float2 c = boxb[n];
        bool valid = clsb[n] > 0;
        unsigned long long mask = __ballot(valid);
        int base = 0;
        if (lane == 0) base = atomicAdd(&cnt, __popcll(mask));
        base = __shfl(base, 0);
        if (valid) {
            int pos = base + __popcll(mask & ((1ULL << lane) - 1ULL));
            cen[pos] = c;
        }
    }
    __syncthreads();

    const int M  = cnt;
    const int Mp = (M + 127) & ~127;     // pad to x128 -> CH multiple of 8
    if (tid < Mp - M) cen[M + tid] = make_float2(1e18f, 1e18f);  // exp -> 0
    __syncthreads();

    // ---- Phase 2: min-d2 scan, wave-chunked ----
    const float px = (float)lane;
    const float py = (float)row;
    const int CH   = Mp >> 4;            // centers per wave (multiple of 8)
    const int cbase = wave * CH;

    float m0 = 3.4e38f, m1 = 3.4e38f, m2 = 3.4e38f, m3 = 3.4e38f;
    #pragma unroll 2
    for (int i = 0; i < CH; i += 4) {
        float2 c0 = cen[cbase + i + 0];
        float2 c1 = cen[cbase + i + 1];
        float2 c2 = cen[cbase + i + 2];
        float2 c3 = cen[cbase + i + 3];
        float dx, dy, d2;
        dx = px - c0.x; dy = py - c0.y; d2 = dx*dx + dy*dy; m0 = fminf(m0, d2);
        dx = px - c1.x; dy = py - c1.y; d2 = dx*dx + dy*dy; m1 = fminf(m1, d2);
        dx = px - c2.x; dy = py - c2.y; d2 = dx*dx + dy*dy; m2 = fminf(m2, d2);
        dx = px - c3.x; dy = py - c3.y; d2 = dx*dx + dy*dy; m3 = fminf(m3, d2);
    }
    red[tid] = fminf(fminf(m0, m1), fminf(m2, m3));
    __syncthreads();

    // ---- Phase 3: combine + loss partial (wave 0 only) ----
    if (tid < 64) {
        float m = red[tid];
        #pragma unroll
        for (int s = 1; s < 16; ++s) m = fminf(m, red[tid + s * 64]);
        float heat = expf(-m * 0.125f);               // sigma=2 -> /(2*4)
        float a = att[(size_t)b * NPIX + row * NW + tid];
        float s = 1.0f / (1.0f + expf(-a));
        float d = s - heat;
        float sq = d * d;
        #pragma unroll
        for (int off = 32; off > 0; off >>= 1)
            sq += __shfl_down(sq, off);
        if (tid == 0) partial[blk] = sq;
    }
}

// One wave: 64 lanes x float4 = 256 partials, shuffle-reduce, scale, store.
__global__ __launch_bounds__(64) void cal_final_kernel(
    const float* __restrict__ partial,  // [256]
    float* __restrict__ out)            // [1]
{
    const int lane = threadIdx.x;
    float4 p = ((const float4*)partial)[lane];
    float v = (p.x + p.y) + (p.z + p.w);
    #pragma unroll
    for (int off = 32; off > 0; off >>= 1)
        v += __shfl_down(v, off);
    if (lane == 0)
        out[0] = v * (0.05f / (float)(NB * NPIX));
}

extern "C" void kernel_launch(void* const* d_in, const int* in_sizes, int n_in,
                              void* d_out, int out_size, void* d_ws, size_t ws_size,
                              hipStream_t stream) {
    const float* att = (const float*)d_in[0];   // attention_maps [4,1,64,64] f32
    const int*   cls = (const int*)  d_in[1];   // class_targets  [4,64,64]  i32
    const float* box = (const float*)d_in[2];   // box_targets    [4,64,64,2] f32
    float* out = (float*)d_out;
    float* partial = (float*)d_ws;              // 256 floats

    cal_main_kernel<<<NB * NH, 1024, 0, stream>>>(att, cls, box, partial);
    cal_final_kernel<<<1, 64, 0, stream>>>(partial, out);
}

// Round 3
// 11.374 us; speedup vs baseline: 1.8159x; 1.1893x over previous
//
#include <hip/hip_runtime.h>

#define NB 4
#define NH 64
#define NW 64
#define NPIX (NH * NW)   // 4096 pixels per batch
#define NCEN NPIX        // 4096 candidate centers per batch
#define SEGCAP 264       // per-wave compacted segment capacity (256 + pad8)
// Centers with (py-cy)^2 > DY2_CUT contribute heat < exp(-170/8)=5.9e-10:
// invisible at the 2.3e-4 absmax threshold on the scalar loss.
#define DY2_CUT 170.0f

// Grid = 256 blocks (one per (batch,row)), 1024 threads = 16 waves (4/SIMD).
// Wave w: compacts centers [w*256, w*256+256) of this batch that are valid
// (cls>0) AND within the dy row band into its own LDS segment (no cross-wave
// atomics, no barrier needed before scanning its own segment), then scans
// that segment for per-pixel min-d2. One barrier, 16-way fmin combine,
// heat=exp(-min_d2/8), fused sigmoid + sq-err, 64-lane shuffle sum.
__global__ __launch_bounds__(1024) void cal_main_kernel(
    const float* __restrict__ att,   // [B,1,H,W] logits
    const int*   __restrict__ cls,   // [B,H,W]
    const float* __restrict__ box,   // [B,H,W,2] (cx,cy)
    float* __restrict__ partial)     // [NB*NH]
{
    __shared__ float2 cen[16 * SEGCAP];  // 33 KiB, per-wave segments
    __shared__ float  red[16][64];       // per-wave per-pixel min-d2

    const int blk  = blockIdx.x;
    const int b    = blk >> 6;           // batch
    const int row  = blk & 63;           // y
    const int tid  = threadIdx.x;
    const int lane = tid & 63;
    const int wave = tid >> 6;           // 0..15

    const float py = (float)row;
    const float px = (float)lane;

    // ---- Phase 1: per-wave band-filtered compaction (atomic-free) ----
    const float2* boxb = (const float2*)(box + (size_t)b * NCEN * 2);
    const int*    clsb = cls + (size_t)b * NCEN;
    const int segBase = wave * SEGCAP;
    const unsigned long long lmask_lt = (1ULL << lane) - 1ULL;

    int cnt = 0;
    #pragma unroll
    for (int i = 0; i < 4; ++i) {
        int n = (wave << 8) + (i << 6) + lane;
        float2 c = boxb[n];
        float dy = py - c.y;
        bool valid = (clsb[n] > 0) & (dy * dy <= DY2_CUT);
        unsigned long long mask = __ballot(valid);
        if (valid) {
            int pos = cnt + __popcll(mask & lmask_lt);
            cen[segBase + pos] = c;
        }
        cnt += __popcll(mask);
    }
    int cntPad = (cnt + 7) & ~7;         // pad to x8 for float4 scanning
    if (lane < cntPad - cnt)
        cen[segBase + cnt + lane] = make_float2(1e18f, 1e18f);  // exp -> 0

    // ---- Phase 2: scan OWN segment (no barrier needed) ----
    const float4* cen4 = (const float4*)&cen[segBase];  // 2 centers / float4
    float m0 = 3.4e38f, m1 = 3.4e38f, m2 = 3.4e38f, m3 = 3.4e38f;
    for (int j = 0; j < cntPad; j += 8) {
        float4 u = cen4[(j >> 1) + 0];
        float4 v = cen4[(j >> 1) + 1];
        float4 w = cen4[(j >> 1) + 2];
        float4 x = cen4[(j >> 1) + 3];
        float dx, dy, d2;
        dx = px - u.x; dy = py - u.y; d2 = fmaf(dy, dy, dx * dx); m0 = fminf(m0, d2);
        dx = px - u.z; dy = py - u.w; d2 = fmaf(dy, dy, dx * dx); m1 = fminf(m1, d2);
        dx = px - v.x; dy = py - v.y; d2 = fmaf(dy, dy, dx * dx); m2 = fminf(m2, d2);
        dx = px - v.z; dy = py - v.w; d2 = fmaf(dy, dy, dx * dx); m3 = fminf(m3, d2);
        dx = px - w.x; dy = py - w.y; d2 = fmaf(dy, dy, dx * dx); m0 = fminf(m0, d2);
        dx = px - w.z; dy = py - w.w; d2 = fmaf(dy, dy, dx * dx); m1 = fminf(m1, d2);
        dx = px - x.x; dy = py - x.y; d2 = fmaf(dy, dy, dx * dx); m2 = fminf(m2, d2);
        dx = px - x.z; dy = py - x.w; d2 = fmaf(dy, dy, dx * dx); m3 = fminf(m3, d2);
    }
    red[wave][lane] = fminf(fminf(m0, m1), fminf(m2, m3));
    __syncthreads();

    // ---- Phase 3: combine + loss partial (wave 0 only) ----
    if (tid < 64) {
        float m = red[0][lane];
        #pragma unroll
        for (int s = 1; s < 16; ++s) m = fminf(m, red[s][lane]);
        float heat = expf(-m * 0.125f);              // sigma=2 -> /(2*4)
        float a = att[(size_t)b * NPIX + row * NW + lane];
        float sg = 1.0f / (1.0f + expf(-a));
        float d = sg - heat;
        float sq = d * d;
        #pragma unroll
        for (int off = 32; off > 0; off >>= 1)
            sq += __shfl_down(sq, off);
        if (lane == 0) partial[blk] = sq;
    }
}

// One wave: 64 lanes x float4 = 256 partials, shuffle-reduce, scale, store.
__global__ __launch_bounds__(64) void cal_final_kernel(
    const float* __restrict__ partial,  // [256]
    float* __restrict__ out)            // [1]
{
    const int lane = threadIdx.x;
    float4 p = ((const float4*)partial)[lane];
    float v = (p.x + p.y) + (p.z + p.w);
    #pragma unroll
    for (int off = 32; off > 0; off >>= 1)
        v += __shfl_down(v, off);
    if (lane == 0)
        out[0] = v * (0.05f / (float)(NB * NPIX));
}

extern "C" void kernel_launch(void* const* d_in, const int* in_sizes, int n_in,
                              void* d_out, int out_size, void* d_ws, size_t ws_size,
                              hipStream_t stream) {
    const float* att = (const float*)d_in[0];   // attention_maps [4,1,64,64] f32
    const int*   cls = (const int*)  d_in[1];   // class_targets  [4,64,64]  i32
    const float* box = (const float*)d_in[2];   // box_targets    [4,64,64,2] f32
    float* out = (float*)d_out;
    float* partial = (float*)d_ws;              // 256 floats

    cal_main_kernel<<<NB * NH, 1024, 0, stream>>>(att, cls, box, partial);
    cal_final_kernel<<<1, 64, 0, stream>>>(partial, out);
}